// Round 3
// baseline (408.149 us; speedup 1.0000x reference)
//
#include <hip/hip_runtime.h>
#include <stdint.h>

// Problem constants: x [B=2, S=4096, K=4096] -> M = 8192; weight [N=4096, K=4096]
#define M_DIM 8192
#define N_DIM 4096
#define K_DIM 4096

using int4v = __attribute__((ext_vector_type(4))) int;

// ---------------------------------------------------------------------------
// Pack kernel: int32 (widened int8 in [-127,127]) -> int8 bytes.
// ---------------------------------------------------------------------------
__global__ __launch_bounds__(256) void pack_kernel(const int4* __restrict__ sx,
                                                   const int4* __restrict__ sw,
                                                   unsigned int* __restrict__ dst,
                                                   int nx, int ntot) {
    int idx = blockIdx.x * blockDim.x + threadIdx.x;
    if (idx >= ntot) return;
    int4 v = (idx < nx) ? sx[idx] : sw[idx - nx];
    dst[idx] = (v.x & 0xff) | ((v.y & 0xff) << 8) | ((v.z & 0xff) << 16) |
               ((v.w & 0xff) << 24);
}

// ---------------------------------------------------------------------------
// Async global -> LDS copy, 16 B per lane (global_load_lds_dwordx4).
// ---------------------------------------------------------------------------
__device__ __forceinline__ void async_copy16(const char* g, char* l) {
    __builtin_amdgcn_global_load_lds(
        (const __attribute__((address_space(1))) char*)g,
        (__attribute__((address_space(3))) char*)l, 16, 0, 0);
}

// ---------------------------------------------------------------------------
// 256(M) x 128(N) i8 GEMM, BK=64, 2 blocks/CU (r3).
// R2 post-mortem: at 1 block/CU the 2 waves/SIMD are barrier-locked in the
// same phase -> LDS-read head (~1000 cyc) and MFMA burst (~2600 cyc)
// SERIALIZE (measured 5475 cyc/K-tile ~= sum of pipes). Fix: occupancy.
// Two independent blocks per CU sit in different phases, so one block's
// MFMAs cover the other's fragment reads and vmcnt(0)+barrier drains.
//
// Budget for 2 blocks/CU: LDS 48 KiB/block (2dbuf x (A 16K + B 8K)),
// VGPR+AGPR <= 128/wave (acc 64 + frags 32 + addr ~20) -> 4 waves/SIMD.
// 512 threads = 8 waves (4M x 2N), wave tile 64x64 = 4x4 grid of 16x16
// MFMA (mfma_i32_16x16x64_i8, one K=64 substep per K-step).
//
// Per K-step per CU (model): MFMA pipe 1305 cyc/SIMD, LDS pipe ~1375 cyc
// -> balanced; 2-block overlap hides the serial heads.
//
// LDS swizzle (r0-verified family, 0 conflicts): 16-B chunk (row, g) holds
// global col-group g ^ ((row>>1)&3); source pre-swizzled, reads XOR-correct.
// ---------------------------------------------------------------------------
__global__ __launch_bounds__(512, 4) void gemm_i8_kernel(
    const char* __restrict__ Aq,   // [M, K] int8
    const char* __restrict__ Bq,   // [N, K] int8
    const int* __restrict__ bias,  // [N] int32 (widened int8)
    const float* __restrict__ a_ptr,
    const float* __restrict__ b_ptr,
    int32_t* __restrict__ out)     // [M, N] int32 holding int8 values
{
    __shared__ char As0[256 * 64];   // 16 KiB
    __shared__ char As1[256 * 64];
    __shared__ char Bs0[128 * 64];   // 8 KiB
    __shared__ char Bs1[128 * 64];

    const int tid  = threadIdx.x;
    const int lane = tid & 63;
    const int wave = tid >> 6;
    const int wr   = wave >> 1;   // 0..3 -> 64 M-rows each
    const int wc   = wave & 1;    // 0..1 -> 64 N-cols each

    // XCD swizzle, square-ish chunks: 1024 blocks = 8 XCDs x 128. Per XCD:
    // 8 M-tiles x 16 N-tiles -> A 8 MB + B 8 MB footprint (L2/L3 friendly).
    const int bid = blockIdx.x;
    const int xcd = bid & 7;      // dispatch round-robins XCDs
    const int lin = bid >> 3;     // 0..127 within this XCD's chunk
    const int mt  = (xcd & 3) * 8 + (lin & 7);     // 0..31
    const int nt  = (xcd >> 2) * 16 + (lin >> 3);  // 0..31
    const int m0  = mt * 256;
    const int n0  = nt * 128;

    const float alpha = *a_ptr;
    const float beta  = *b_ptr;

    int4v acc[4][4] = {};   // 64 accumulator regs

    // Fragment read coords: lane holds op row m = lane&15, k-group = lane>>4.
    const int fr   = lane & 15;
    const int gw   = lane >> 4;
    const int koff = ((gw ^ ((fr >> 1) & 3)) << 4);
    const int aoff = (wr * 64 + fr) * 64 + koff;   // byte offset into As*
    const int boff = (wc * 64 + fr) * 64 + koff;   // byte offset into Bs*

    // Staging: thread t owns 16-B chunk (row = t>>2, stored col g = t&3);
    // global col-group = g ^ ((row>>1)&3) = (t&3) ^ ((t>>3)&3) pre-swizzles.
    const int srow = tid >> 2;                               // 0..127
    const int scg  = ((tid & 3) ^ ((tid >> 3) & 3)) << 4;    // byte col offset
    const char* gA0 = Aq + (size_t)(m0 + srow) * K_DIM + scg;
    const char* gA1 = gA0 + (size_t)128 * K_DIM;             // rows 128..255
    const char* gB0 = Bq + (size_t)(n0 + srow) * K_DIM + scg;

    // A dst: row r col g -> byte r*64+g*16 = t*16 (rows 0..127), 8192+t*16
    // (rows 128..255). B dst: t*16. All linear in t (global_load_lds rule).
#define STAGE(AS, BS, t)                                                     \
    {                                                                        \
        const size_t off_ = (size_t)(t) * 64;                                \
        async_copy16(gA0 + off_, &AS[tid * 16]);                             \
        async_copy16(gA1 + off_, &AS[8192 + tid * 16]);                      \
        async_copy16(gB0 + off_, &BS[tid * 16]);                             \
    }

    // 8 ds_read_b128 + 16 MFMA; compiler interleaves with counted lgkmcnt.
#define COMPUTE(AS, BS)                                                      \
    {                                                                        \
        int4v af[4], bf[4];                                                  \
        _Pragma("unroll") for (int i = 0; i < 4; ++i)                        \
            af[i] = *(const int4v*)&AS[aoff + i * 1024];                     \
        _Pragma("unroll") for (int j = 0; j < 4; ++j)                        \
            bf[j] = *(const int4v*)&BS[boff + j * 1024];                     \
        __builtin_amdgcn_s_setprio(1);                                       \
        _Pragma("unroll") for (int i = 0; i < 4; ++i)                        \
        _Pragma("unroll") for (int j = 0; j < 4; ++j)                        \
            acc[i][j] = __builtin_amdgcn_mfma_i32_16x16x64_i8(               \
                af[i], bf[j], acc[i][j], 0, 0, 0);                           \
        __builtin_amdgcn_s_setprio(0);                                       \
    }

    // Drain this step's 3 staging loads (issued before COMPUTE -> ~1300 cyc
    // of cover), then barrier. The other resident block computes meanwhile.
#define STEP_END                                                             \
    {                                                                        \
        asm volatile("s_waitcnt vmcnt(0)" ::: "memory");                     \
        __builtin_amdgcn_s_barrier();                                        \
        __builtin_amdgcn_sched_barrier(0);                                   \
    }

    // Prologue: stage step 0 into buf0 (latency exposed once).
    STAGE(As0, Bs0, 0);
    STEP_END;

#pragma unroll 1
    for (int it = 0; it < 31; ++it) {
        // step 2it (buf0): stage step 2it+1 -> buf1, then compute buf0.
        STAGE(As1, Bs1, 2 * it + 1);
        __builtin_amdgcn_sched_barrier(0);
        COMPUTE(As0, Bs0);
        STEP_END;
        // step 2it+1 (buf1): stage 2it+2 -> buf0, compute buf1.
        STAGE(As0, Bs0, 2 * it + 2);
        __builtin_amdgcn_sched_barrier(0);
        COMPUTE(As1, Bs1);
        STEP_END;
    }
    // step 62 (buf0): stage final step 63 -> buf1.
    STAGE(As1, Bs1, 63);
    __builtin_amdgcn_sched_barrier(0);
    COMPUTE(As0, Bs0);
    STEP_END;
    // step 63 (buf1): compute only.
    COMPUTE(As1, Bs1);

    // Epilogue: C/D layout col = lane&15, row = (lane>>4)*4 + reg.
    const int orow = (lane >> 4) * 4;
    const int ocol = lane & 15;
#pragma unroll
    for (int j = 0; j < 4; ++j) {
        const int gn = n0 + wc * 64 + j * 16 + ocol;
        const float bb = beta * (float)bias[gn];
#pragma unroll
        for (int i = 0; i < 4; ++i) {
            const int gm = m0 + wr * 64 + i * 16 + orow;
#pragma unroll
            for (int r = 0; r < 4; ++r) {
                float v = alpha * (float)acc[i][j][r] + bb;
                v = rintf(v);                       // round half-to-even (numpy)
                v = fminf(fmaxf(v, -128.0f), 127.0f);
                out[(size_t)(gm + r) * N_DIM + gn] = (int32_t)v;
            }
        }
    }
}

// ---------------------------------------------------------------------------
extern "C" void kernel_launch(void* const* d_in, const int* in_sizes, int n_in,
                              void* d_out, int out_size, void* d_ws, size_t ws_size,
                              hipStream_t stream) {
    const int*   x    = (const int*)d_in[0];    // [M, K] widened int8
    const int*   w    = (const int*)d_in[1];    // [N, K] widened int8
    const int*   bias = (const int*)d_in[2];    // [N]
    const float* a    = (const float*)d_in[3];  // alpha scalar
    const float* b    = (const float*)d_in[4];  // beta scalar
    int32_t*     out  = (int32_t*)d_out;        // [M, N]

    char* xq = (char*)d_ws;                     // 32 MiB packed x
    const int nx   = (M_DIM * K_DIM) / 4;       // int4-groups in x
    const int nw   = (N_DIM * K_DIM) / 4;
    const int ntot = nx + nw;
    pack_kernel<<<(ntot + 255) / 256, 256, 0, stream>>>(
        (const int4*)x, (const int4*)w, (unsigned int*)xq, nx, ntot);

    char* wq = xq + (size_t)M_DIM * K_DIM;      // 16 MiB packed weight

    dim3 grid((M_DIM / 256) * (N_DIM / 128));   // 1024 blocks, 1D for XCD swizzle
    gemm_i8_kernel<<<grid, 512, 0, stream>>>(xq, wq, bias, a, b, out);
}

// Round 4
// 403.464 us; speedup vs baseline: 1.0116x; 1.0116x over previous
//
#include <hip/hip_runtime.h>
#include <stdint.h>

// Problem constants: x [B=2, S=4096, K=4096] -> M = 8192; weight [N=4096, K=4096]
#define M_DIM 8192
#define N_DIM 4096
#define K_DIM 4096

using int4v = __attribute__((ext_vector_type(4))) int;

// ---------------------------------------------------------------------------
// Pack kernel: int32 (widened int8 in [-127,127]) -> int8 bytes.
// ---------------------------------------------------------------------------
__global__ __launch_bounds__(256) void pack_kernel(const int4* __restrict__ sx,
                                                   const int4* __restrict__ sw,
                                                   unsigned int* __restrict__ dst,
                                                   int nx, int ntot) {
    int idx = blockIdx.x * blockDim.x + threadIdx.x;
    if (idx >= ntot) return;
    int4 v = (idx < nx) ? sx[idx] : sw[idx - nx];
    dst[idx] = (v.x & 0xff) | ((v.y & 0xff) << 8) | ((v.z & 0xff) << 16) |
               ((v.w & 0xff) << 24);
}

// ---------------------------------------------------------------------------
// Async global -> LDS copy, 16 B per lane (global_load_lds_dwordx4).
// ---------------------------------------------------------------------------
__device__ __forceinline__ void async_copy16(const char* g, char* l) {
    __builtin_amdgcn_global_load_lds(
        (const __attribute__((address_space(1))) char*)g,
        (__attribute__((address_space(3))) char*)l, 16, 0, 0);
}

// ---------------------------------------------------------------------------
// 256(M) x 128(N) i8 GEMM, BK=64, TRIPLE-buffered staging, 2 blocks/CU (r4).
// R0-R3 post-mortem: all 2-buffer schedules cap at MfmaUtil ~40% because the
// staging drain is structural: loads for tile t+1 issue at the top of tile t
// and drain at its bottom -- slack is only the body's wave-time ISSUE cost
// (~300-500 cyc), below L2/HBM completion latency (~200-900 cyc + queueing).
// Every step all waves block with the matrix pipe holding ~320 cyc of work.
// Fix (m201's actual mechanism): keep 2 tiles in flight, drain with COUNTED
// vmcnt(3) -- completes only tile t+1; tile t+2's loads get a full extra
// K-step (~1500 cyc) to land. No wave should ever stall on staging.
//
// 512 threads = 8 waves (4M x 2N), wave tile 64x64 = 4x4 grid of 16x16 MFMA
// (mfma_i32_16x16x64_i8). LDS: 3 x (A 16K + B 8K) = 72 KiB -> 2 blocks/CU
// (VGPR 64 + 64 AGPR -> 4 waves/SIMD).
//
// LDS swizzle (verified family, 0 conflicts): 16-B chunk (row, g) holds
// global col-group g ^ ((row>>1)&3); source pre-swizzled, reads XOR-correct.
// ---------------------------------------------------------------------------
__global__ __launch_bounds__(512, 4) void gemm_i8_kernel(
    const char* __restrict__ Aq,   // [M, K] int8
    const char* __restrict__ Bq,   // [N, K] int8
    const int* __restrict__ bias,  // [N] int32 (widened int8)
    const float* __restrict__ a_ptr,
    const float* __restrict__ b_ptr,
    int32_t* __restrict__ out)     // [M, N] int32 holding int8 values
{
    __shared__ char As0[256 * 64];   // 16 KiB each
    __shared__ char As1[256 * 64];
    __shared__ char As2[256 * 64];
    __shared__ char Bs0[128 * 64];   // 8 KiB each
    __shared__ char Bs1[128 * 64];
    __shared__ char Bs2[128 * 64];

    const int tid  = threadIdx.x;
    const int lane = tid & 63;
    const int wave = tid >> 6;
    const int wr   = wave >> 1;   // 0..3 -> 64 M-rows each
    const int wc   = wave & 1;    // 0..1 -> 64 N-cols each

    // XCD swizzle, square chunks: 1024 blocks = 8 XCDs x 128. Per XCD:
    // 8 M-tiles x 16 N-tiles -> A 8 MB + B 8 MB footprint.
    const int bid = blockIdx.x;
    const int xcd = bid & 7;
    const int lin = bid >> 3;
    const int mt  = (xcd & 3) * 8 + (lin & 7);     // 0..31
    const int nt  = (xcd >> 2) * 16 + (lin >> 3);  // 0..31
    const int m0  = mt * 256;
    const int n0  = nt * 128;

    const float alpha = *a_ptr;
    const float beta  = *b_ptr;

    int4v acc[4][4] = {};   // 64 accumulator regs (AGPR)

    // Fragment read coords: lane holds op row m = lane&15, k-group = lane>>4.
    const int fr   = lane & 15;
    const int gw   = lane >> 4;
    const int koff = ((gw ^ ((fr >> 1) & 3)) << 4);
    const int aoff = (wr * 64 + fr) * 64 + koff;
    const int boff = (wc * 64 + fr) * 64 + koff;

    // Staging: thread t owns 16-B chunk (row = t>>2, stored col g = t&3);
    // global col-group = g ^ ((row>>1)&3) = (t&3) ^ ((t>>3)&3) pre-swizzles.
    const int srow = tid >> 2;                               // 0..127
    const int scg  = ((tid & 3) ^ ((tid >> 3) & 3)) << 4;
    const char* gA0 = Aq + (size_t)(m0 + srow) * K_DIM + scg;
    const char* gA1 = gA0 + (size_t)128 * K_DIM;             // rows 128..255
    const char* gB0 = Bq + (size_t)(n0 + srow) * K_DIM + scg;

#define STAGE(AS, BS, t)                                                     \
    {                                                                        \
        const size_t off_ = (size_t)(t) * 64;                                \
        async_copy16(gA0 + off_, &AS[tid * 16]);                             \
        async_copy16(gA1 + off_, &AS[8192 + tid * 16]);                      \
        async_copy16(gB0 + off_, &BS[tid * 16]);                             \
        __builtin_amdgcn_sched_barrier(0);                                   \
    }

    // 8 ds_read_b128 + 16 MFMA; compiler interleaves with counted lgkmcnt.
#define COMPUTE(AS, BS)                                                      \
    {                                                                        \
        int4v af[4], bf[4];                                                  \
        _Pragma("unroll") for (int i = 0; i < 4; ++i)                        \
            af[i] = *(const int4v*)&AS[aoff + i * 1024];                     \
        _Pragma("unroll") for (int j = 0; j < 4; ++j)                        \
            bf[j] = *(const int4v*)&BS[boff + j * 1024];                     \
        __builtin_amdgcn_s_setprio(1);                                       \
        _Pragma("unroll") for (int i = 0; i < 4; ++i)                        \
        _Pragma("unroll") for (int j = 0; j < 4; ++j)                        \
            acc[i][j] = __builtin_amdgcn_mfma_i32_16x16x64_i8(               \
                af[i], bf[j], acc[i][j], 0, 0, 0);                           \
        __builtin_amdgcn_s_setprio(0);                                       \
    }

    // Counted drain: 6 loads in flight (t+1: 3, t+2: 3); vmcnt(3) completes
    // only the in-order-older tile t+1. t+2 keeps flying a full extra step.
#define STEP_END_CNT                                                         \
    {                                                                        \
        asm volatile("s_waitcnt vmcnt(3)" ::: "memory");                     \
        __builtin_amdgcn_s_barrier();                                        \
        __builtin_amdgcn_sched_barrier(0);                                   \
    }

#define STEP_END_ALL                                                         \
    {                                                                        \
        asm volatile("s_waitcnt vmcnt(0)" ::: "memory");                     \
        __builtin_amdgcn_s_barrier();                                        \
        __builtin_amdgcn_sched_barrier(0);                                   \
    }

    // Prologue: stage tiles 0,1; wait tile 0 only (vmcnt(3) leaves t1 flying).
    STAGE(As0, Bs0, 0);
    STAGE(As1, Bs1, 1);
    asm volatile("s_waitcnt vmcnt(3)" ::: "memory");
    __builtin_amdgcn_s_barrier();
    __builtin_amdgcn_sched_barrier(0);

    // Steps t = 0..59 in groups of 3 (static buffer indexing, rule #20).
#pragma unroll 1
    for (int i = 0; i < 20; ++i) {
        const int t = 3 * i;
        STAGE(As2, Bs2, t + 2);
        COMPUTE(As0, Bs0);
        STEP_END_CNT;
        STAGE(As0, Bs0, t + 3);
        COMPUTE(As1, Bs1);
        STEP_END_CNT;
        STAGE(As1, Bs1, t + 4);
        COMPUTE(As2, Bs2);
        STEP_END_CNT;
    }
    // t=60 (buf0): stage 62 -> buf2; wait completes t61.
    STAGE(As2, Bs2, 62);
    COMPUTE(As0, Bs0);
    STEP_END_CNT;
    // t=61 (buf1): stage 63 -> buf0; wait completes t62.
    STAGE(As0, Bs0, 63);
    COMPUTE(As1, Bs1);
    STEP_END_CNT;
    // t=62 (buf2): drain everything (t63).
    COMPUTE(As2, Bs2);
    STEP_END_ALL;
    // t=63 (buf0): compute only.
    COMPUTE(As0, Bs0);

    // Epilogue: C/D layout col = lane&15, row = (lane>>4)*4 + reg.
    const int orow = (lane >> 4) * 4;
    const int ocol = lane & 15;
#pragma unroll
    for (int j = 0; j < 4; ++j) {
        const int gn = n0 + wc * 64 + j * 16 + ocol;
        const float bb = beta * (float)bias[gn];
#pragma unroll
        for (int i = 0; i < 4; ++i) {
            const int gm = m0 + wr * 64 + i * 16 + orow;
#pragma unroll
            for (int r = 0; r < 4; ++r) {
                float v = alpha * (float)acc[i][j][r] + bb;
                v = rintf(v);                       // round half-to-even (numpy)
                v = fminf(fmaxf(v, -128.0f), 127.0f);
                out[(size_t)(gm + r) * N_DIM + gn] = (int32_t)v;
            }
        }
    }
}

// ---------------------------------------------------------------------------
extern "C" void kernel_launch(void* const* d_in, const int* in_sizes, int n_in,
                              void* d_out, int out_size, void* d_ws, size_t ws_size,
                              hipStream_t stream) {
    const int*   x    = (const int*)d_in[0];    // [M, K] widened int8
    const int*   w    = (const int*)d_in[1];    // [N, K] widened int8
    const int*   bias = (const int*)d_in[2];    // [N]
    const float* a    = (const float*)d_in[3];  // alpha scalar
    const float* b    = (const float*)d_in[4];  // beta scalar
    int32_t*     out  = (int32_t*)d_out;        // [M, N]

    char* xq = (char*)d_ws;                     // 32 MiB packed x
    const int nx   = (M_DIM * K_DIM) / 4;       // int4-groups in x
    const int nw   = (N_DIM * K_DIM) / 4;
    const int ntot = nx + nw;
    pack_kernel<<<(ntot + 255) / 256, 256, 0, stream>>>(
        (const int4*)x, (const int4*)w, (unsigned int*)xq, nx, ntot);

    char* wq = xq + (size_t)M_DIM * K_DIM;      // 16 MiB packed weight

    dim3 grid((M_DIM / 256) * (N_DIM / 128));   // 1024 blocks, 1D for XCD swizzle
    gemm_i8_kernel<<<grid, 512, 0, stream>>>(xq, wq, bias, a, b, out);
}

// Round 5
// 401.351 us; speedup vs baseline: 1.0169x; 1.0053x over previous
//
#include <hip/hip_runtime.h>
#include <stdint.h>

// Problem constants: x [B=2, S=4096, K=4096] -> M = 8192; weight [N=4096, K=4096]
#define M_DIM 8192
#define N_DIM 4096
#define K_DIM 4096

using int4v = __attribute__((ext_vector_type(4))) int;

// ---------------------------------------------------------------------------
// Pack kernel: int32 (widened int8 in [-127,127]) -> int8 bytes.
// ---------------------------------------------------------------------------
__global__ __launch_bounds__(256) void pack_kernel(const int4* __restrict__ sx,
                                                   const int4* __restrict__ sw,
                                                   unsigned int* __restrict__ dst,
                                                   int nx, int ntot) {
    int idx = blockIdx.x * blockDim.x + threadIdx.x;
    if (idx >= ntot) return;
    int4 v = (idx < nx) ? sx[idx] : sw[idx - nx];
    dst[idx] = (v.x & 0xff) | ((v.y & 0xff) << 8) | ((v.z & 0xff) << 16) |
               ((v.w & 0xff) << 24);
}

// ---------------------------------------------------------------------------
// Async global -> LDS copy, 16 B per lane (global_load_lds_dwordx4).
// ---------------------------------------------------------------------------
__device__ __forceinline__ void async_copy16(const char* g, char* l) {
    __builtin_amdgcn_global_load_lds(
        (const __attribute__((address_space(1))) char*)g,
        (__attribute__((address_space(3))) char*)l, 16, 0, 0);
}

// ---------------------------------------------------------------------------
// 256x256 i8 GEMM, 4 waves, WAVE TILE 128x128 (r5).
// R0-R4 post-mortem: every schedule variant (2-barrier, 8-phase, 2-block,
// triple-buffer) lands at 35-40% MfmaUtil because the kernel is LDS-READ
// bound, not schedule bound: 64x64 wave tiles give 33 MACs per LDS byte;
// per K-step the LDS pipe (~1600-1900 cyc) exceeds the MFMA pipe (1306 cyc)
// and no interleave can beat the max-pipe floor. Fix the TRAFFIC:
// 128x128 wave tile -> 65 MACs/LDS-byte; fragment reads halve to 64 KB/CU
// per K-step (~600 cyc) and the MFMA pipe becomes the critical path.
//
// Cost: acc 8x8 int4v = 256 regs -> ~360 VGPR+AGPR -> 1 wave/SIMD. That is
// fine: each wave owns 64 MFMA (~1306 cyc of matrix-pipe work) per step,
// plenty of ILP for the compiler's counted-lgkmcnt interleave to hide its
// 16 ds_read_b128 under. LDS: 3 buf x (A 16K + B 16K) = 96 KiB, 1 block/CU.
// Triple-buffered staging with counted vmcnt(8) (r4) keeps staging off the
// critical path.
//
// LDS swizzle (verified family, 0 conflicts measured in r3/r4): 16-B chunk
// (row, g) holds global col-group g ^ ((row>>1)&3); source pre-swizzled,
// reads XOR-correct.
// ---------------------------------------------------------------------------
__global__ __launch_bounds__(256, 1) void gemm_i8_kernel(
    const char* __restrict__ Aq,   // [M, K] int8
    const char* __restrict__ Bq,   // [N, K] int8
    const int* __restrict__ bias,  // [N] int32 (widened int8)
    const float* __restrict__ a_ptr,
    const float* __restrict__ b_ptr,
    int32_t* __restrict__ out)     // [M, N] int32 holding int8 values
{
    __shared__ char As0[256 * 64];   // 16 KiB each
    __shared__ char As1[256 * 64];
    __shared__ char As2[256 * 64];
    __shared__ char Bs0[256 * 64];
    __shared__ char Bs1[256 * 64];
    __shared__ char Bs2[256 * 64];

    const int tid  = threadIdx.x;
    const int lane = tid & 63;
    const int wave = tid >> 6;
    const int wr   = wave >> 1;   // 0..1 -> 128 M-rows
    const int wc   = wave & 1;    // 0..1 -> 128 N-cols

    // XCD swizzle, square chunks: 512 blocks = 8 XCDs x 64. Per XCD:
    // 8 M-tiles x 8 N-tiles -> A 8 MB + B 8 MB footprint (L3-resident).
    const int bid = blockIdx.x;
    const int xcd = bid & 7;
    const int lin = bid >> 3;                      // 0..63
    const int mt  = (xcd & 3) * 8 + (lin & 7);     // 0..31
    const int nt  = (xcd >> 2) * 8 + (lin >> 3);   // 0..15
    const int m0  = mt * 256;
    const int n0  = nt * 256;

    const float alpha = *a_ptr;
    const float beta  = *b_ptr;

    int4v acc[8][8] = {};   // 256 accumulator regs (AGPR)

    // Fragment read coords: lane holds op row m = lane&15, k-group = lane>>4.
    const int fr   = lane & 15;
    const int gw   = lane >> 4;
    const int koff = ((gw ^ ((fr >> 1) & 3)) << 4);
    const int aoff = (wr * 128 + fr) * 64 + koff;
    const int boff = (wc * 128 + fr) * 64 + koff;

    // Staging: thread t owns 16-B chunks (row = t>>2 + 64h, stored col t&3)
    // for h = 0..3; global col-group = (t&3) ^ ((t>>3)&3) (swizzle key is
    // invariant under row += 64). LDS dst = 4096h + t*16 -- linear in t.
    const int srow = tid >> 2;                               // 0..63
    const int scg  = ((tid & 3) ^ ((tid >> 3) & 3)) << 4;
    const char* gA = Aq + (size_t)(m0 + srow) * K_DIM + scg;
    const char* gB = Bq + (size_t)(n0 + srow) * K_DIM + scg;

#define STAGE(AS, BS, t)                                                     \
    {                                                                        \
        const size_t off_ = (size_t)(t) * 64;                                \
        _Pragma("unroll") for (int h = 0; h < 4; ++h)                        \
            async_copy16(gA + (size_t)(64 * h) * K_DIM + off_,               \
                         &AS[4096 * h + tid * 16]);                          \
        _Pragma("unroll") for (int h = 0; h < 4; ++h)                        \
            async_copy16(gB + (size_t)(64 * h) * K_DIM + off_,               \
                         &BS[4096 * h + tid * 16]);                          \
        __builtin_amdgcn_sched_barrier(0);                                   \
    }

    // 16 ds_read_b128 + 64 MFMA; compiler interleaves with counted lgkmcnt.
    // Every fragment is reused 8x -> 65 MACs per LDS byte.
#define COMPUTE(AS, BS)                                                      \
    {                                                                        \
        int4v af[8], bf[8];                                                  \
        _Pragma("unroll") for (int i = 0; i < 8; ++i)                        \
            af[i] = *(const int4v*)&AS[aoff + i * 1024];                     \
        _Pragma("unroll") for (int j = 0; j < 8; ++j)                        \
            bf[j] = *(const int4v*)&BS[boff + j * 1024];                     \
        __builtin_amdgcn_s_setprio(1);                                       \
        _Pragma("unroll") for (int i = 0; i < 8; ++i)                        \
        _Pragma("unroll") for (int j = 0; j < 8; ++j)                        \
            acc[i][j] = __builtin_amdgcn_mfma_i32_16x16x64_i8(               \
                af[i], bf[j], acc[i][j], 0, 0, 0);                           \
        __builtin_amdgcn_s_setprio(0);                                       \
    }

    // Counted drain: 16 loads in flight (t+1: 8, t+2: 8); vmcnt(8) completes
    // only the older tile. The newer tile keeps flying a full extra step.
#define STEP_END_CNT                                                         \
    {                                                                        \
        asm volatile("s_waitcnt vmcnt(8)" ::: "memory");                     \
        __builtin_amdgcn_s_barrier();                                        \
        __builtin_amdgcn_sched_barrier(0);                                   \
    }

    // Prologue: stage tiles 0,1; wait tile 0 only.
    STAGE(As0, Bs0, 0);
    STAGE(As1, Bs1, 1);
    asm volatile("s_waitcnt vmcnt(8)" ::: "memory");
    __builtin_amdgcn_s_barrier();
    __builtin_amdgcn_sched_barrier(0);

    // Steps t = 0..59 in groups of 3 (static buffer indexing).
#pragma unroll 1
    for (int i = 0; i < 20; ++i) {
        const int t = 3 * i;
        STAGE(As2, Bs2, t + 2);
        COMPUTE(As0, Bs0);
        STEP_END_CNT;
        STAGE(As0, Bs0, t + 3);
        COMPUTE(As1, Bs1);
        STEP_END_CNT;
        STAGE(As1, Bs1, t + 4);
        COMPUTE(As2, Bs2);
        STEP_END_CNT;
    }
    // t=60 (buf0): stage 62 -> buf2; wait completes t61.
    STAGE(As2, Bs2, 62);
    COMPUTE(As0, Bs0);
    STEP_END_CNT;
    // t=61 (buf1): stage 63 -> buf0; wait completes t62.
    STAGE(As0, Bs0, 63);
    COMPUTE(As1, Bs1);
    STEP_END_CNT;
    // t=62 (buf2): drain everything (t63).
    COMPUTE(As2, Bs2);
    asm volatile("s_waitcnt vmcnt(0)" ::: "memory");
    __builtin_amdgcn_s_barrier();
    __builtin_amdgcn_sched_barrier(0);
    // t=63 (buf0): compute only.
    COMPUTE(As0, Bs0);

    // Epilogue: C/D layout col = lane&15, row = (lane>>4)*4 + reg.
    const int orow = (lane >> 4) * 4;
    const int ocol = lane & 15;
#pragma unroll
    for (int j = 0; j < 8; ++j) {
        const int gn = n0 + wc * 128 + j * 16 + ocol;
        const float bb = beta * (float)bias[gn];
#pragma unroll
        for (int i = 0; i < 8; ++i) {
            const int gm = m0 + wr * 128 + i * 16 + orow;
#pragma unroll
            for (int r = 0; r < 4; ++r) {
                float v = alpha * (float)acc[i][j][r] + bb;
                v = rintf(v);                       // round half-to-even (numpy)
                v = fminf(fmaxf(v, -128.0f), 127.0f);
                out[(size_t)(gm + r) * N_DIM + gn] = (int32_t)v;
            }
        }
    }
}

// ---------------------------------------------------------------------------
extern "C" void kernel_launch(void* const* d_in, const int* in_sizes, int n_in,
                              void* d_out, int out_size, void* d_ws, size_t ws_size,
                              hipStream_t stream) {
    const int*   x    = (const int*)d_in[0];    // [M, K] widened int8
    const int*   w    = (const int*)d_in[1];    // [N, K] widened int8
    const int*   bias = (const int*)d_in[2];    // [N]
    const float* a    = (const float*)d_in[3];  // alpha scalar
    const float* b    = (const float*)d_in[4];  // beta scalar
    int32_t*     out  = (int32_t*)d_out;        // [M, N]

    char* xq = (char*)d_ws;                     // 32 MiB packed x
    const int nx   = (M_DIM * K_DIM) / 4;       // int4-groups in x
    const int nw   = (N_DIM * K_DIM) / 4;
    const int ntot = nx + nw;
    pack_kernel<<<(ntot + 255) / 256, 256, 0, stream>>>(
        (const int4*)x, (const int4*)w, (unsigned int*)xq, nx, ntot);

    char* wq = xq + (size_t)M_DIM * K_DIM;      // 16 MiB packed weight

    dim3 grid((M_DIM / 256) * (N_DIM / 256));   // 512 blocks, 1D for XCD swizzle
    gemm_i8_kernel<<<grid, 256, 0, stream>>>(xq, wq, bias, a, b, out);
}